// Round 3
// baseline (3986.703 us; speedup 1.0000x reference)
//
#include <hip/hip_runtime.h>
#include <math.h>

#define D_MODEL 2048
#define NHEAD 16
#define HDIM 128
#define SQL 1024
#define SKVL 2560

// ---------------- RMSNorm (row per block) ----------------
__global__ __launch_bounds__(256) void rms_kernel(
    const float* __restrict__ X, const float* __restrict__ w, float* __restrict__ Y)
{
    int row = blockIdx.x;
    const float4* x4 = (const float4*)(X + (size_t)row * D_MODEL);
    const float4* w4 = (const float4*)w;
    float4* y4 = (float4*)(Y + (size_t)row * D_MODEL);
    __shared__ float red[256];
    float s = 0.f;
    for (int i = threadIdx.x; i < D_MODEL / 4; i += 256) {
        float4 v = x4[i];
        s += v.x * v.x + v.y * v.y + v.z * v.z + v.w * v.w;
    }
    red[threadIdx.x] = s; __syncthreads();
    for (int st = 128; st > 0; st >>= 1) {
        if (threadIdx.x < st) red[threadIdx.x] += red[threadIdx.x + st];
        __syncthreads();
    }
    float r = rsqrtf(red[0] * (1.f / D_MODEL) + 1e-6f);
    for (int i = threadIdx.x; i < D_MODEL / 4; i += 256) {
        float4 v = x4[i], ww = w4[i];
        float4 o;
        o.x = v.x * r * ww.x; o.y = v.y * r * ww.y;
        o.z = v.z * r * ww.z; o.w = v.w * r * ww.w;
        y4[i] = o;
    }
}

// ---------------- LayerNorm (row per block, two-pass) ----------------
__global__ __launch_bounds__(256) void ln_kernel(
    const float* __restrict__ X, const float* __restrict__ g, const float* __restrict__ b,
    float* __restrict__ Y)
{
    int row = blockIdx.x;
    const float4* x4 = (const float4*)(X + (size_t)row * D_MODEL);
    __shared__ float red[256];
    float s = 0.f;
    for (int i = threadIdx.x; i < D_MODEL / 4; i += 256) {
        float4 v = x4[i];
        s += v.x + v.y + v.z + v.w;
    }
    red[threadIdx.x] = s; __syncthreads();
    for (int st = 128; st > 0; st >>= 1) {
        if (threadIdx.x < st) red[threadIdx.x] += red[threadIdx.x + st];
        __syncthreads();
    }
    float mu = red[0] * (1.f / D_MODEL);
    __syncthreads();
    float vv = 0.f;
    for (int i = threadIdx.x; i < D_MODEL / 4; i += 256) {
        float4 v = x4[i];
        float a0 = v.x - mu, a1 = v.y - mu, a2 = v.z - mu, a3 = v.w - mu;
        vv += a0 * a0 + a1 * a1 + a2 * a2 + a3 * a3;
    }
    red[threadIdx.x] = vv; __syncthreads();
    for (int st = 128; st > 0; st >>= 1) {
        if (threadIdx.x < st) red[threadIdx.x] += red[threadIdx.x + st];
        __syncthreads();
    }
    float rstd = rsqrtf(red[0] * (1.f / D_MODEL) + 1e-5f);
    const float4* g4 = (const float4*)g;
    const float4* b4 = (const float4*)b;
    float4* y4 = (float4*)(Y + (size_t)row * D_MODEL);
    for (int i = threadIdx.x; i < D_MODEL / 4; i += 256) {
        float4 v = x4[i], gg = g4[i], bb = b4[i];
        float4 o;
        o.x = (v.x - mu) * rstd * gg.x + bb.x;
        o.y = (v.y - mu) * rstd * gg.y + bb.y;
        o.z = (v.z - mu) * rstd * gg.z + bb.z;
        o.w = (v.w - mu) * rstd * gg.w + bb.w;
        y4[i] = o;
    }
}

// ---------------- fp32 GEMM: C[orow(r)] = epi(A[r,:] @ W + ...) ----------------
// EPI: 0 = acc+bias ; 1 = res + tanh(g)*(acc+bias) ; 2 = gelu(acc) ; 3 = res + tanh(g)*acc
// out row mapping: orow = (r/Sin)*Sout + rowOff + (r%Sin)   (handles concat K/V layout)
template <int EPI>
__global__ __launch_bounds__(256) void gemm_kernel(
    const float* __restrict__ A, const float* __restrict__ W,
    const float* __restrict__ bias, float* __restrict__ C,
    int M, int N, int K, int Sin, int Sout, int rowOff,
    const float* __restrict__ res, const float* __restrict__ gate)
{
    __shared__ float As[16][68];  // [k][m] transposed, pad 68 -> 2-way max (free)
    __shared__ float Bs[16][64];  // [k][n]
    const int t = threadIdx.x;
    const int tq = t >> 4, tn = t & 15;
    const int bm = blockIdx.y * 64, bn = blockIdx.x * 64;
    const int am = t >> 2, ak4 = (t & 3) << 2;   // A stage: 64 rows x 16 cols
    const int kb = t >> 4, nb4 = (t & 15) << 2;  // B stage: 16 rows x 64 cols
    float acc[4][4] = {};
    for (int kt = 0; kt < K; kt += 16) {
        float4 a4 = *(const float4*)(A + (size_t)(bm + am) * K + kt + ak4);
        float4 b4 = *(const float4*)(W + (size_t)(kt + kb) * N + bn + nb4);
        As[ak4 + 0][am] = a4.x; As[ak4 + 1][am] = a4.y;
        As[ak4 + 2][am] = a4.z; As[ak4 + 3][am] = a4.w;
        *(float4*)&Bs[kb][nb4] = b4;
        __syncthreads();
#pragma unroll
        for (int k = 0; k < 16; ++k) {
            float4 av = *(const float4*)&As[k][tq << 2];
            float4 bv = *(const float4*)&Bs[k][tn << 2];
            float aa[4] = {av.x, av.y, av.z, av.w};
            float bb[4] = {bv.x, bv.y, bv.z, bv.w};
#pragma unroll
            for (int i = 0; i < 4; ++i)
#pragma unroll
                for (int j = 0; j < 4; ++j)
                    acc[i][j] = fmaf(aa[i], bb[j], acc[i][j]);
        }
        __syncthreads();
    }
    float tg = 0.f;
    if (EPI == 1 || EPI == 3) tg = tanhf(gate[0]);
#pragma unroll
    for (int i = 0; i < 4; ++i) {
        int r = bm + (tq << 2) + i;
        int orow = (r / Sin) * Sout + rowOff + (r % Sin);
        float vout[4];
#pragma unroll
        for (int j = 0; j < 4; ++j) {
            float v = acc[i][j];
            if (EPI == 0 || EPI == 1) v += bias[bn + (tn << 2) + j];
            if (EPI == 2) v = 0.5f * v * (1.f + erff(v * 0.70710678118654752f));
            vout[j] = v;
        }
        if (EPI == 1 || EPI == 3) {
            const float4 rv = *(const float4*)(res + (size_t)orow * N + bn + (tn << 2));
            vout[0] = rv.x + tg * vout[0];
            vout[1] = rv.y + tg * vout[1];
            vout[2] = rv.z + tg * vout[2];
            vout[3] = rv.w + tg * vout[3];
        }
        float4 o; o.x = vout[0]; o.y = vout[1]; o.z = vout[2]; o.w = vout[3];
        *(float4*)(C + (size_t)orow * N + bn + (tn << 2)) = o;
    }
}

// ---------------- Flash attention (fp32, online softmax) ----------------
// grid: (SQL/64, B*H). block 256. QT=64 rows, KV chunks of 32.
__global__ __launch_bounds__(256) void attn_kernel(
    const float* __restrict__ Q, const float* __restrict__ K, const float* __restrict__ V,
    const float* __restrict__ mp, const float* __restrict__ ms, const float* __restrict__ mm,
    float* __restrict__ O)
{
    __shared__ float Qs[128][68];   // [d][q], scaled by 0.25
    __shared__ float Ks[128][36];   // [d][kv]
    __shared__ float Vs[32][132];   // [kv][d]
    __shared__ float Ps[32][68];    // [kv][q]
    __shared__ float mk[32];
    const int t = threadIdx.x;
    const int b = blockIdx.y >> 4;
    const int h = blockIdx.y & 15;
    const int q0 = blockIdx.x * 64;
    {   // stage Q transposed (uncoalesced global gather, L2-resident; conflict-free LDS)
        int qi = t & 63, d0 = t >> 6;
        const float* qp = Q + ((size_t)(b * SQL + q0 + qi)) * D_MODEL + h * HDIM;
#pragma unroll
        for (int i = 0; i < 32; ++i) {
            int d = d0 + (i << 2);
            Qs[d][qi] = qp[d] * 0.25f;  // scale = H^-0.5 = 0.25 (ref scales by num_heads)
        }
    }
    const int tq = t >> 4, tn = t & 15;
    float m_r[4], l_r[4], o_acc[4][8];
#pragma unroll
    for (int i = 0; i < 4; ++i) {
        m_r[i] = -1e30f; l_r[i] = 0.f;
#pragma unroll
        for (int d = 0; d < 8; ++d) o_acc[i][d] = 0.f;
    }
    __syncthreads();

    for (int kv0 = 0; kv0 < SKVL; kv0 += 32) {
        {   // stage K transposed
            int ki = t & 31, d0 = t >> 5;
            const float* kp = K + ((size_t)(b * SKVL + kv0 + ki)) * D_MODEL + h * HDIM;
#pragma unroll
            for (int i = 0; i < 16; ++i) {
                int d = d0 + (i << 3);
                Ks[d][ki] = kp[d];
            }
        }
#pragma unroll
        for (int i = 0; i < 4; ++i) {  // stage V (coalesced float4)
            int f4 = t + (i << 8);
            int vi = f4 >> 5, d4 = (f4 & 31) << 2;
            *(float4*)&Vs[vi][d4] =
                *(const float4*)(V + ((size_t)(b * SKVL + kv0 + vi)) * D_MODEL + h * HDIM + d4);
        }
        if (t < 32) {
            int kvg = kv0 + t;
            float mv;
            if (kvg < 1024) mv = mp[b * 1024 + kvg];
            else if (kvg < 2048) mv = ms[b * 1024 + (kvg - 1024)];
            else mv = mm[b * 512 + (kvg - 2048)];
            mk[t] = mv;
        }
        __syncthreads();
        // S[4q][2kv]
        float s[4][2] = {};
        for (int d = 0; d < 128; ++d) {
            float4 qv = *(const float4*)&Qs[d][tq << 2];
            float2 kv2 = *(const float2*)&Ks[d][tn << 1];
            float qa[4] = {qv.x, qv.y, qv.z, qv.w};
#pragma unroll
            for (int i = 0; i < 4; ++i) {
                s[i][0] = fmaf(qa[i], kv2.x, s[i][0]);
                s[i][1] = fmaf(qa[i], kv2.y, s[i][1]);
            }
        }
        float mk0 = mk[tn << 1], mk1 = mk[(tn << 1) + 1];
        float alpha[4];
#pragma unroll
        for (int i = 0; i < 4; ++i) {
            float s0 = (mk0 == 0.f) ? -1e30f : s[i][0];
            float s1 = (mk1 == 0.f) ? -1e30f : s[i][1];
            float mx = fmaxf(s0, s1);
#pragma unroll
            for (int off = 1; off < 16; off <<= 1) mx = fmaxf(mx, __shfl_xor(mx, off, 64));
            float mnew = fmaxf(m_r[i], mx);
            alpha[i] = expf(m_r[i] - mnew);
            float p0 = expf(s0 - mnew), p1 = expf(s1 - mnew);
            float ps = p0 + p1;
#pragma unroll
            for (int off = 1; off < 16; off <<= 1) ps += __shfl_xor(ps, off, 64);
            m_r[i] = mnew;
            l_r[i] = l_r[i] * alpha[i] + ps;
            Ps[tn << 1][(tq << 2) + i] = p0;
            Ps[(tn << 1) + 1][(tq << 2) + i] = p1;
        }
        __syncthreads();
#pragma unroll
        for (int i = 0; i < 4; ++i)
#pragma unroll
            for (int dd = 0; dd < 8; ++dd) o_acc[i][dd] *= alpha[i];
        for (int kv = 0; kv < 32; ++kv) {
            float4 pv = *(const float4*)&Ps[kv][tq << 2];
            float4 va = *(const float4*)&Vs[kv][tn << 3];
            float4 vb = *(const float4*)&Vs[kv][(tn << 3) + 4];
            float pa[4] = {pv.x, pv.y, pv.z, pv.w};
            float vaa[4] = {va.x, va.y, va.z, va.w};
            float vbb[4] = {vb.x, vb.y, vb.z, vb.w};
#pragma unroll
            for (int i = 0; i < 4; ++i)
#pragma unroll
                for (int dd = 0; dd < 4; ++dd) {
                    o_acc[i][dd]     = fmaf(pa[i], vaa[dd], o_acc[i][dd]);
                    o_acc[i][dd + 4] = fmaf(pa[i], vbb[dd], o_acc[i][dd + 4]);
                }
        }
        __syncthreads();
    }
#pragma unroll
    for (int i = 0; i < 4; ++i) {
        float inv = 1.f / l_r[i];
        float* op = O + ((size_t)(b * SQL + q0 + (tq << 2) + i)) * D_MODEL + h * HDIM + (tn << 3);
        float4 o1, o2;
        o1.x = o_acc[i][0] * inv; o1.y = o_acc[i][1] * inv;
        o1.z = o_acc[i][2] * inv; o1.w = o_acc[i][3] * inv;
        o2.x = o_acc[i][4] * inv; o2.y = o_acc[i][5] * inv;
        o2.z = o_acc[i][6] * inv; o2.w = o_acc[i][7] * inv;
        *(float4*)op = o1; *(float4*)(op + 4) = o2;
    }
}

extern "C" void kernel_launch(void* const* d_in, const int* in_sizes, int n_in,
                              void* d_out, int out_size, void* d_ws, size_t ws_size,
                              hipStream_t stream)
{
    (void)in_sizes; (void)n_in; (void)out_size; (void)ws_size;
    const float* qs   = (const float*)d_in[0];
    const float* pkv  = (const float*)d_in[1];
    const float* skvi = (const float*)d_in[2];
    const float* mkvi = (const float*)d_in[3];
    const float* mskp = (const float*)d_in[5];
    const float* msks = (const float*)d_in[6];
    const float* mskm = (const float*)d_in[7];
    const float* rmsw = (const float*)d_in[8];
    const float* Wq  = (const float*)d_in[9];  const float* bq  = (const float*)d_in[10];
    const float* Wkp = (const float*)d_in[11]; const float* bkp = (const float*)d_in[12];
    const float* Wvp = (const float*)d_in[13]; const float* bvp = (const float*)d_in[14];
    const float* Wks = (const float*)d_in[15]; const float* bks = (const float*)d_in[16];
    const float* Wvs = (const float*)d_in[17]; const float* bvs = (const float*)d_in[18];
    const float* Wkm = (const float*)d_in[19]; const float* bkm = (const float*)d_in[20];
    const float* Wvm = (const float*)d_in[21]; const float* bvm = (const float*)d_in[22];
    const float* Wo  = (const float*)d_in[23]; const float* bo  = (const float*)d_in[24];
    const float* lng = (const float*)d_in[25]; const float* lnb = (const float*)d_in[26];
    const float* W1  = (const float*)d_in[27]; const float* W2  = (const float*)d_in[28];
    const float* ga  = (const float*)d_in[29]; const float* gf  = (const float*)d_in[30];

    float* ws = (float*)d_ws;
    const size_t SZ_Q  = (size_t)2048 * 2048;        // 4.19M floats
    const size_t SZ_KV = (size_t)2 * SKVL * D_MODEL; // 10.49M floats
    float* qn  = ws;                  // rmsnorm out        (later aliased by ctx)
    float* qb  = ws + SZ_Q;           // q proj             (later aliased by xln)
    float* kb  = ws + 2 * SZ_Q;       // K concat [B,2560,2048] (later aliased by FFN mid)
    float* vb  = kb + SZ_KV;          // V concat
    float* hb  = vb + SZ_KV;          // h residual
    float* ctx = qn;
    float* xln = qb;
    float* tb  = kb;                  // FFN intermediate [2048, 8192] fits in K+V region

    dim3 blk(256);
    rms_kernel<<<2048, blk, 0, stream>>>(qs, rmsw, qn);
    gemm_kernel<0><<<dim3(32, 32), blk, 0, stream>>>(qn, Wq, bq, qb,
        2048, 2048, 2048, 2048, 2048, 0, nullptr, nullptr);
    gemm_kernel<0><<<dim3(32, 32), blk, 0, stream>>>(pkv, Wkp, bkp, kb,
        2048, 2048, 1280, 1024, SKVL, 0, nullptr, nullptr);
    gemm_kernel<0><<<dim3(32, 32), blk, 0, stream>>>(skvi, Wks, bks, kb,
        2048, 2048, 1024, 1024, SKVL, 1024, nullptr, nullptr);
    gemm_kernel<0><<<dim3(32, 16), blk, 0, stream>>>(mkvi, Wkm, bkm, kb,
        1024, 2048, 768, 512, SKVL, 2048, nullptr, nullptr);
    gemm_kernel<0><<<dim3(32, 32), blk, 0, stream>>>(pkv, Wvp, bvp, vb,
        2048, 2048, 1280, 1024, SKVL, 0, nullptr, nullptr);
    gemm_kernel<0><<<dim3(32, 32), blk, 0, stream>>>(skvi, Wvs, bvs, vb,
        2048, 2048, 1024, 1024, SKVL, 1024, nullptr, nullptr);
    gemm_kernel<0><<<dim3(32, 16), blk, 0, stream>>>(mkvi, Wvm, bvm, vb,
        1024, 2048, 768, 512, SKVL, 2048, nullptr, nullptr);
    attn_kernel<<<dim3(16, 32), blk, 0, stream>>>(qb, kb, vb, mskp, msks, mskm, ctx);
    gemm_kernel<1><<<dim3(32, 32), blk, 0, stream>>>(ctx, Wo, bo, hb,
        2048, 2048, 2048, 2048, 2048, 0, qs, ga);
    ln_kernel<<<2048, blk, 0, stream>>>(hb, lng, lnb, xln);
    gemm_kernel<2><<<dim3(128, 32), blk, 0, stream>>>(xln, W1, nullptr, tb,
        2048, 8192, 2048, 2048, 2048, 0, nullptr, nullptr);
    gemm_kernel<3><<<dim3(32, 32), blk, 0, stream>>>(tb, W2, nullptr, (float*)d_out,
        2048, 2048, 8192, 2048, 2048, 0, hb, gf);
}